// Round 5
// baseline (439.361 us; speedup 1.0000x reference)
//
#include <hip/hip_runtime.h>
#include <hip/hip_cooperative_groups.h>
#include <math.h>

namespace cg = cooperative_groups;

#define H 2048

__device__ __forceinline__ float sigmoidf_(float v) {
    return 1.0f / (1.0f + expf(-v));
}

__device__ __forceinline__ float wave_reduce_sum(float v) {
    v += __shfl_down(v, 32, 64);
    v += __shfl_down(v, 16, 64);
    v += __shfl_down(v, 8, 64);
    v += __shfl_down(v, 4, 64);
    v += __shfl_down(v, 2, 64);
    v += __shfl_down(v, 1, 64);
    return v;
}

// One cooperative kernel for the whole decoder.
// Grid: 256 blocks x 512 thr = 2048 waves; wave (blockIdx*8 + wid) owns
// output element t across ALL layers. Dependency-aware phasing:
//   Phase A: Whh0.h0p, Whh1.h1p, Whh2.h2p (201 MB, independent) + finish layer0
//   Phase B: Wih1.h0 (67 MB) + finish layer1
//   Phase C: Wih2.h1 (67 MB) + finish layer2
//   Phase D: y = Wout.h2 + bout (block 0)
// Whh1/Whh2 partials stay in REGISTERS across grid.sync(); only h vectors
// cross waves (via d_ws, 16B-aligned; d_out+1 is misaligned for float4).
__global__ __launch_bounds__(512, 2)
void lstm_all(const float* __restrict__ xs,
              const float* __restrict__ hin,   // [3H]
              const float* __restrict__ cin,   // [3H]
              const float* __restrict__ Wih0,  // [4H]
              const float* __restrict__ Whh0,  // [4H,H]
              const float* __restrict__ bih0, const float* __restrict__ bhh0,
              const float* __restrict__ Wih1, const float* __restrict__ Whh1,
              const float* __restrict__ bih1, const float* __restrict__ bhh1,
              const float* __restrict__ Wih2, const float* __restrict__ Whh2,
              const float* __restrict__ bih2, const float* __restrict__ bhh2,
              const float* __restrict__ Wout, const float* __restrict__ bout,
              float* __restrict__ out,         // [1 + 3H + 3H]
              float* __restrict__ hws)         // [3*H] aligned h storage
{
    cg::grid_group grid = cg::this_grid();
    const int wid  = threadIdx.x >> 6;          // 0..7
    const int lane = threadIdx.x & 63;
    const int t    = blockIdx.x * 8 + wid;      // 0..2047

    float* yout = out;
    float* hN   = out + 1;
    float* cN   = out + 1 + 3 * H;

    float p1[4], p2[4];   // Whh1/Whh2 partials, live across grid syncs

    // ---------------- Phase A: all Whh products + finish layer 0 ----------
    {
        float4 hv[8];
        const float4* h4 = (const float4*)hin;
#pragma unroll
        for (int k = 0; k < 8; ++k) hv[k] = h4[lane + 64 * k];

        float g0[4];
#pragma unroll 1
        for (int g = 0; g < 4; ++g) {
            const float4* wr = (const float4*)(Whh0 + (size_t)(g * H + t) * H);
            float a = 0.0f;
#pragma unroll
            for (int k = 0; k < 8; ++k) {
                float4 w = wr[lane + 64 * k];
                a += w.x * hv[k].x + w.y * hv[k].y + w.z * hv[k].z + w.w * hv[k].w;
            }
            g0[g] = wave_reduce_sum(a);
        }
        if (lane == 0) {
            const float x = xs[0];
            float gi = g0[0] + x * Wih0[t]         + bih0[t]         + bhh0[t];
            float gf = g0[1] + x * Wih0[H + t]     + bih0[H + t]     + bhh0[H + t];
            float gg = g0[2] + x * Wih0[2 * H + t] + bih0[2 * H + t] + bhh0[2 * H + t];
            float go = g0[3] + x * Wih0[3 * H + t] + bih0[3 * H + t] + bhh0[3 * H + t];
            float c2 = sigmoidf_(gf) * cin[t] + sigmoidf_(gi) * tanhf(gg);
            float h2 = sigmoidf_(go) * tanhf(c2);
            cN[t] = c2; hN[t] = h2; hws[t] = h2;
        }

        // layer 1 recurrent partials
        h4 = (const float4*)(hin + H);
#pragma unroll
        for (int k = 0; k < 8; ++k) hv[k] = h4[lane + 64 * k];
#pragma unroll 1
        for (int g = 0; g < 4; ++g) {
            const float4* wr = (const float4*)(Whh1 + (size_t)(g * H + t) * H);
            float a = 0.0f;
#pragma unroll
            for (int k = 0; k < 8; ++k) {
                float4 w = wr[lane + 64 * k];
                a += w.x * hv[k].x + w.y * hv[k].y + w.z * hv[k].z + w.w * hv[k].w;
            }
            p1[g] = wave_reduce_sum(a);
        }

        // layer 2 recurrent partials
        h4 = (const float4*)(hin + 2 * H);
#pragma unroll
        for (int k = 0; k < 8; ++k) hv[k] = h4[lane + 64 * k];
#pragma unroll 1
        for (int g = 0; g < 4; ++g) {
            const float4* wr = (const float4*)(Whh2 + (size_t)(g * H + t) * H);
            float a = 0.0f;
#pragma unroll
            for (int k = 0; k < 8; ++k) {
                float4 w = wr[lane + 64 * k];
                a += w.x * hv[k].x + w.y * hv[k].y + w.z * hv[k].z + w.w * hv[k].w;
            }
            p2[g] = wave_reduce_sum(a);
        }
    }
    grid.sync();

    // ---------------- Phase B: Wih1 . h0, finish layer 1 ------------------
    {
        float4 xv[8];
        const float4* x4 = (const float4*)hws;  // h0
#pragma unroll
        for (int k = 0; k < 8; ++k) xv[k] = x4[lane + 64 * k];
        float s[4];
#pragma unroll 1
        for (int g = 0; g < 4; ++g) {
            const float4* wr = (const float4*)(Wih1 + (size_t)(g * H + t) * H);
            float a = 0.0f;
#pragma unroll
            for (int k = 0; k < 8; ++k) {
                float4 w = wr[lane + 64 * k];
                a += w.x * xv[k].x + w.y * xv[k].y + w.z * xv[k].z + w.w * xv[k].w;
            }
            s[g] = wave_reduce_sum(a);
        }
        if (lane == 0) {
            float gi = s[0] + p1[0] + bih1[t]         + bhh1[t];
            float gf = s[1] + p1[1] + bih1[H + t]     + bhh1[H + t];
            float gg = s[2] + p1[2] + bih1[2 * H + t] + bhh1[2 * H + t];
            float go = s[3] + p1[3] + bih1[3 * H + t] + bhh1[3 * H + t];
            float c2 = sigmoidf_(gf) * cin[H + t] + sigmoidf_(gi) * tanhf(gg);
            float h2 = sigmoidf_(go) * tanhf(c2);
            cN[H + t] = c2; hN[H + t] = h2; hws[H + t] = h2;
        }
    }
    grid.sync();

    // ---------------- Phase C: Wih2 . h1, finish layer 2 ------------------
    {
        float4 xv[8];
        const float4* x4 = (const float4*)(hws + H);  // h1
#pragma unroll
        for (int k = 0; k < 8; ++k) xv[k] = x4[lane + 64 * k];
        float s[4];
#pragma unroll 1
        for (int g = 0; g < 4; ++g) {
            const float4* wr = (const float4*)(Wih2 + (size_t)(g * H + t) * H);
            float a = 0.0f;
#pragma unroll
            for (int k = 0; k < 8; ++k) {
                float4 w = wr[lane + 64 * k];
                a += w.x * xv[k].x + w.y * xv[k].y + w.z * xv[k].z + w.w * xv[k].w;
            }
            s[g] = wave_reduce_sum(a);
        }
        if (lane == 0) {
            float gi = s[0] + p2[0] + bih2[t]         + bhh2[t];
            float gf = s[1] + p2[1] + bih2[H + t]     + bhh2[H + t];
            float gg = s[2] + p2[2] + bih2[2 * H + t] + bhh2[2 * H + t];
            float go = s[3] + p2[3] + bih2[3 * H + t] + bhh2[3 * H + t];
            float c2 = sigmoidf_(gf) * cin[2 * H + t] + sigmoidf_(gi) * tanhf(gg);
            float h2 = sigmoidf_(go) * tanhf(c2);
            cN[2 * H + t] = c2; hN[2 * H + t] = h2; hws[2 * H + t] = h2;
        }
    }
    grid.sync();

    // ---------------- Phase D: y = Wout . h2 + bout (block 0) -------------
    if (blockIdx.x == 0) {
        __shared__ float partl[8];
        const int tid = threadIdx.x;             // 0..511
        const float4* W4 = (const float4*)Wout;
        const float4* h4 = (const float4*)(hws + 2 * H);
        float4 a = W4[tid];
        float4 b = h4[tid];
        float acc = a.x * b.x + a.y * b.y + a.z * b.z + a.w * b.w;
        acc = wave_reduce_sum(acc);
        if (lane == 0) partl[wid] = acc;
        __syncthreads();
        if (tid == 0) {
            float s = bout[0];
#pragma unroll
            for (int i = 0; i < 8; ++i) s += partl[i];
            yout[0] = s;
        }
    }
}

extern "C" void kernel_launch(void* const* d_in, const int* in_sizes, int n_in,
                              void* d_out, int out_size, void* d_ws, size_t ws_size,
                              hipStream_t stream) {
    const float* x    = (const float*)d_in[0];
    const float* hin  = (const float*)d_in[1];
    const float* cin  = (const float*)d_in[2];
    const float* Wih0 = (const float*)d_in[3];
    const float* Whh0 = (const float*)d_in[4];
    const float* bih0 = (const float*)d_in[5];
    const float* bhh0 = (const float*)d_in[6];
    const float* Wih1 = (const float*)d_in[7];
    const float* Whh1 = (const float*)d_in[8];
    const float* bih1 = (const float*)d_in[9];
    const float* bhh1 = (const float*)d_in[10];
    const float* Wih2 = (const float*)d_in[11];
    const float* Whh2 = (const float*)d_in[12];
    const float* bih2 = (const float*)d_in[13];
    const float* bhh2 = (const float*)d_in[14];
    const float* Wout = (const float*)d_in[15];
    const float* bout = (const float*)d_in[16];

    float* out = (float*)d_out;
    float* hws = (float*)d_ws;   // 3*H floats, 16B-aligned

    void* args[] = {
        (void*)&x, (void*)&hin, (void*)&cin,
        (void*)&Wih0, (void*)&Whh0, (void*)&bih0, (void*)&bhh0,
        (void*)&Wih1, (void*)&Whh1, (void*)&bih1, (void*)&bhh1,
        (void*)&Wih2, (void*)&Whh2, (void*)&bih2, (void*)&bhh2,
        (void*)&Wout, (void*)&bout,
        (void*)&out, (void*)&hws
    };
    hipLaunchCooperativeKernel((void*)lstm_all, dim3(256), dim3(512),
                               args, 0, stream);
}

// Round 6
// 340.013 us; speedup vs baseline: 1.2922x; 1.2922x over previous
//
#include <hip/hip_runtime.h>
#include <math.h>

#define H 2048

__device__ __forceinline__ float sigmoidf_(float v) {
    return 1.0f / (1.0f + expf(-v));
}

__device__ __forceinline__ float wave_reduce_sum(float v) {
    v += __shfl_down(v, 32, 64);
    v += __shfl_down(v, 16, 64);
    v += __shfl_down(v, 8, 64);
    v += __shfl_down(v, 4, 64);
    v += __shfl_down(v, 2, 64);
    v += __shfl_down(v, 1, 64);
    return v;
}

// Layers 1,2 — persistent-wave, fully fused. (R4 structure: best measured.)
// 512 blocks x 256 thr = 2048 waves; wave owns output element t.
// x-vec and h-vec live in registers; the g-loop streams TWO rows (Wih+Whh)
// concurrently = 16 loads in flight; no LDS, no barriers.
__global__ __launch_bounds__(256, 2)
void lstm_layer(const float* __restrict__ Wih, const float* __restrict__ Whh,
                const float* __restrict__ bih, const float* __restrict__ bhh,
                const float* __restrict__ xin,  // [H] prev-layer h
                const float* __restrict__ hin,  // [H]
                const float* __restrict__ cin,  // [H]
                float* __restrict__ hout, float* __restrict__ cout)
{
    const int t = blockIdx.x * 4 + (threadIdx.x >> 6);  // 0..2047
    const int lane = threadIdx.x & 63;

    float4 xv[8], hv[8];
    const float4* x4 = (const float4*)xin;
    const float4* h4 = (const float4*)hin;
#pragma unroll
    for (int k = 0; k < 8; ++k) {
        xv[k] = x4[lane + 64 * k];
        hv[k] = h4[lane + 64 * k];
    }

    float gsum[4];
#pragma unroll 1
    for (int g = 0; g < 4; ++g) {
        const float4* wi = (const float4*)(Wih + (size_t)(g * H + t) * H);
        const float4* wh = (const float4*)(Whh + (size_t)(g * H + t) * H);
        float ai = 0.0f, ah = 0.0f;
#pragma unroll
        for (int k = 0; k < 8; ++k) {
            float4 a = wi[lane + 64 * k];
            float4 b = wh[lane + 64 * k];
            ai += a.x * xv[k].x + a.y * xv[k].y + a.z * xv[k].z + a.w * xv[k].w;
            ah += b.x * hv[k].x + b.y * hv[k].y + b.z * hv[k].z + b.w * hv[k].w;
        }
        gsum[g] = wave_reduce_sum(ai + ah);
    }

    if (lane == 0) {
        float gi = gsum[0] + bih[t]         + bhh[t];
        float gf = gsum[1] + bih[H + t]     + bhh[H + t];
        float gg = gsum[2] + bih[2 * H + t] + bhh[2 * H + t];
        float go = gsum[3] + bih[3 * H + t] + bhh[3 * H + t];
        float c2 = sigmoidf_(gf) * cin[t] + sigmoidf_(gi) * tanhf(gg);
        float h2 = sigmoidf_(go) * tanhf(c2);
        cout[t] = c2;
        hout[t] = h2;
    }
}

// Same as lstm_layer, plus the fused output head: lane 0 of each wave adds
// Wout[t]*h2[t] into y via device-scope atomicAdd (y pre-seeded with bout by
// lstm_layer0, which runs earlier in the stream).
__global__ __launch_bounds__(256, 2)
void lstm_layer_last(const float* __restrict__ Wih, const float* __restrict__ Whh,
                     const float* __restrict__ bih, const float* __restrict__ bhh,
                     const float* __restrict__ xin,
                     const float* __restrict__ hin,
                     const float* __restrict__ cin,
                     float* __restrict__ hout, float* __restrict__ cout,
                     const float* __restrict__ Wout,
                     float* __restrict__ y)
{
    const int t = blockIdx.x * 4 + (threadIdx.x >> 6);
    const int lane = threadIdx.x & 63;

    float4 xv[8], hv[8];
    const float4* x4 = (const float4*)xin;
    const float4* h4 = (const float4*)hin;
#pragma unroll
    for (int k = 0; k < 8; ++k) {
        xv[k] = x4[lane + 64 * k];
        hv[k] = h4[lane + 64 * k];
    }

    float gsum[4];
#pragma unroll 1
    for (int g = 0; g < 4; ++g) {
        const float4* wi = (const float4*)(Wih + (size_t)(g * H + t) * H);
        const float4* wh = (const float4*)(Whh + (size_t)(g * H + t) * H);
        float ai = 0.0f, ah = 0.0f;
#pragma unroll
        for (int k = 0; k < 8; ++k) {
            float4 a = wi[lane + 64 * k];
            float4 b = wh[lane + 64 * k];
            ai += a.x * xv[k].x + a.y * xv[k].y + a.z * xv[k].z + a.w * xv[k].w;
            ah += b.x * hv[k].x + b.y * hv[k].y + b.z * hv[k].z + b.w * hv[k].w;
        }
        gsum[g] = wave_reduce_sum(ai + ah);
    }

    if (lane == 0) {
        float gi = gsum[0] + bih[t]         + bhh[t];
        float gf = gsum[1] + bih[H + t]     + bhh[H + t];
        float gg = gsum[2] + bih[2 * H + t] + bhh[2 * H + t];
        float go = gsum[3] + bih[3 * H + t] + bhh[3 * H + t];
        float c2 = sigmoidf_(gf) * cin[t] + sigmoidf_(gi) * tanhf(gg);
        float h2 = sigmoidf_(go) * tanhf(c2);
        cout[t] = c2;
        hout[t] = h2;
        atomicAdd(y, Wout[t] * h2);
    }
}

// Layer 0 — Wih0 is [4H,1]: contribution is x * Wih0[g*H+t], folded in tail.
// Also seeds y = bout (consumed by lstm_layer_last's atomics, stream-ordered).
__global__ __launch_bounds__(256, 2)
void lstm_layer0(const float* __restrict__ Wih0,  // [4H]
                 const float* __restrict__ Whh,   // [4H,H]
                 const float* __restrict__ bih, const float* __restrict__ bhh,
                 const float* __restrict__ xs,    // [1]
                 const float* __restrict__ hin, const float* __restrict__ cin,
                 float* __restrict__ hout, float* __restrict__ cout,
                 const float* __restrict__ bout,
                 float* __restrict__ y)
{
    const int t = blockIdx.x * 4 + (threadIdx.x >> 6);
    const int lane = threadIdx.x & 63;

    if (blockIdx.x == 0 && threadIdx.x == 0) y[0] = bout[0];

    float4 hv[8];
    const float4* h4 = (const float4*)hin;
#pragma unroll
    for (int k = 0; k < 8; ++k) hv[k] = h4[lane + 64 * k];

    float gsum[4];
#pragma unroll 1
    for (int g = 0; g < 4; ++g) {
        const float4* wh = (const float4*)(Whh + (size_t)(g * H + t) * H);
        float a0 = 0.0f, a1 = 0.0f;
#pragma unroll
        for (int k = 0; k < 8; k += 2) {
            float4 a = wh[lane + 64 * k];
            float4 b = wh[lane + 64 * (k + 1)];
            a0 += a.x * hv[k].x + a.y * hv[k].y + a.z * hv[k].z + a.w * hv[k].w;
            a1 += b.x * hv[k+1].x + b.y * hv[k+1].y + b.z * hv[k+1].z + b.w * hv[k+1].w;
        }
        gsum[g] = wave_reduce_sum(a0 + a1);
    }

    if (lane == 0) {
        const float x = xs[0];
        float gi = gsum[0] + x * Wih0[t]         + bih[t]         + bhh[t];
        float gf = gsum[1] + x * Wih0[H + t]     + bih[H + t]     + bhh[H + t];
        float gg = gsum[2] + x * Wih0[2 * H + t] + bih[2 * H + t] + bhh[2 * H + t];
        float go = gsum[3] + x * Wih0[3 * H + t] + bih[3 * H + t] + bhh[3 * H + t];
        float c2 = sigmoidf_(gf) * cin[t] + sigmoidf_(gi) * tanhf(gg);
        float h2 = sigmoidf_(go) * tanhf(c2);
        cout[t] = c2;
        hout[t] = h2;
    }
}

extern "C" void kernel_launch(void* const* d_in, const int* in_sizes, int n_in,
                              void* d_out, int out_size, void* d_ws, size_t ws_size,
                              hipStream_t stream) {
    const float* x    = (const float*)d_in[0];
    const float* hin  = (const float*)d_in[1];   // [3,1,H]
    const float* cin  = (const float*)d_in[2];   // [3,1,H]
    const float* Wih0 = (const float*)d_in[3];
    const float* Whh0 = (const float*)d_in[4];
    const float* bih0 = (const float*)d_in[5];
    const float* bhh0 = (const float*)d_in[6];
    const float* Wih1 = (const float*)d_in[7];
    const float* Whh1 = (const float*)d_in[8];
    const float* bih1 = (const float*)d_in[9];
    const float* bhh1 = (const float*)d_in[10];
    const float* Wih2 = (const float*)d_in[11];
    const float* Whh2 = (const float*)d_in[12];
    const float* bih2 = (const float*)d_in[13];
    const float* bhh2 = (const float*)d_in[14];
    const float* Wout = (const float*)d_in[15];
    const float* bout = (const float*)d_in[16];

    float* out = (float*)d_out;
    float* y  = out;              // [1]
    float* hN = out + 1;          // [3,H]
    float* cN = out + 1 + 3 * H;  // [3,H]

    lstm_layer0<<<512, 256, 0, stream>>>(Wih0, Whh0, bih0, bhh0, x,
                                         hin, cin, hN, cN, bout, y);
    lstm_layer<<<512, 256, 0, stream>>>(Wih1, Whh1, bih1, bhh1,
                                        hN, hin + H, cin + H,
                                        hN + H, cN + H);
    lstm_layer_last<<<512, 256, 0, stream>>>(Wih2, Whh2, bih2, bhh2,
                                             hN + H, hin + 2 * H, cin + 2 * H,
                                             hN + 2 * H, cN + 2 * H,
                                             Wout, y);
}